// Round 1
// baseline (1589.906 us; speedup 1.0000x reference)
//
#include <hip/hip_runtime.h>
#include <hip/hip_bf16.h>

#define ND 30000
#define NT 15000
#define FD 200
#define FT 570
#define HDIM 768
#define EDD 300000
#define EDT 400000
#define ETT 200000

#define KPD 256   // FD padded to x64
#define KPT 576   // FT padded to x64

typedef __attribute__((ext_vector_type(8))) short short8;
typedef __attribute__((ext_vector_type(4))) float float4v;

// ---------------- dtype-adaptive load/store ----------------
// flag[0]: 0 = harness float tensors are bf16, 1 = fp32.

__device__ __forceinline__ float ldx(const void* p, size_t i, int f32) {
  return f32 ? ((const float*)p)[i]
             : __bfloat162float(((const __hip_bfloat16*)p)[i]);
}
__device__ __forceinline__ void stx(void* p, size_t i, int f32, float v) {
  if (f32) ((float*)p)[i] = v;
  else     ((__hip_bfloat16*)p)[i] = __float2bfloat16(v);
}
__device__ __forceinline__ float b2f(unsigned short u) {
  return __uint_as_float(((unsigned)u) << 16);
}
__device__ __forceinline__ unsigned short f2b(float f) {
  __hip_bfloat16 h = __float2bfloat16(f);
  return *(unsigned short*)&h;
}

__device__ __forceinline__ float wave_reduce(float v) {
#pragma unroll
  for (int off = 32; off > 0; off >>= 1) v += __shfl_xor(v, off, 64);
  return v;
}

// ---------------- dtype sniffer ----------------
__global__ void sniff(const void* x, int* flag) {
  int t = threadIdx.x;
  float cnt = 0.f;
  for (int i = t; i < 8192; i += 256) {
    float v = __bfloat162float(((const __hip_bfloat16*)x)[i]);
    if (!(fabsf(v) < 100.f)) cnt += 1.f;  // true for NaN too
  }
  cnt = wave_reduce(cnt);
  __shared__ float red[4];
  if ((t & 63) == 0) red[t >> 6] = cnt;
  __syncthreads();
  if (t == 0) flag[0] = (red[0] + red[1] + red[2] + red[3] > 256.f) ? 1 : 0;
}

// ---------------- va[k] = sum_h W[k,h]*a[h], one wave per k ----------------
__global__ __launch_bounds__(256) void wa_dot(const void* __restrict__ W, const void* __restrict__ a,
                                              float* __restrict__ outv, int fin,
                                              const int* __restrict__ flag) {
  int f32 = flag[0];
  int k = (blockIdx.x * 256 + threadIdx.x) >> 6;
  int lane = threadIdx.x & 63;
  if (k >= fin) return;
  float acc = 0.f;
  for (int h = lane; h < HDIM; h += 64)
    acc += ldx(W, (size_t)k * HDIM + h, f32) * ldx(a, h, f32);
  acc = wave_reduce(acc);
  if (lane == 0) outv[k] = acc;
}

// ---------- 4 dots per row (shared x read), one wave per row ----------
__global__ __launch_bounds__(256) void row_dot4(const void* __restrict__ x,
                                                const int* __restrict__ mask,
                                                const void* __restrict__ tok,
                                                const float* __restrict__ va,
                                                float* __restrict__ outv, int N, int K,
                                                const int* __restrict__ flag) {
  int f32 = flag[0];
  int row = (blockIdx.x * 256 + threadIdx.x) >> 6;
  int lane = threadIdx.x & 63;
  if (row >= N) return;
  bool msk = (mask != nullptr) && (mask[row] != 0);
  float a0 = 0.f, a1 = 0.f, a2 = 0.f, a3 = 0.f;
  for (int k = lane; k < K; k += 64) {
    float v = msk ? ldx(tok, k, f32) : ldx(x, (size_t)row * K + k, f32);
    a0 += v * va[k];
    a1 += v * va[K + k];
    a2 += v * va[2 * K + k];
    a3 += v * va[3 * K + k];
  }
  a0 = wave_reduce(a0); a1 = wave_reduce(a1);
  a2 = wave_reduce(a2); a3 = wave_reduce(a3);
  if (lane == 0) {
    float* o = outv + (size_t)row * 4;
    o[0] = a0; o[1] = a1; o[2] = a2; o[3] = a3;
  }
}

// ---------------- pack A: x_eff -> bf16 [M][Kp], zero-padded K ----------------
__global__ __launch_bounds__(256) void pack_a(const void* __restrict__ x,
                                              const int* __restrict__ mask,
                                              const void* __restrict__ tok,
                                              unsigned short* __restrict__ Aout,
                                              int M, int K, int Kp,
                                              const int* __restrict__ flag) {
  int f32 = flag[0];
  long long gid = (long long)blockIdx.x * 256 + threadIdx.x;
  long long total = (long long)M * Kp / 4;
  if (gid >= total) return;
  long long e0 = gid * 4;
  int row = (int)(e0 / Kp);
  int k = (int)(e0 % Kp);
  bool msk = (mask != nullptr) && (mask[row] != 0);
  ushort4 o;
  unsigned short r[4];
#pragma unroll
  for (int c = 0; c < 4; ++c) {
    int kk = k + c;
    float f = 0.f;
    if (kk < K) f = msk ? ldx(tok, kk, f32) : ldx(x, (size_t)row * K + kk, f32);
    r[c] = f2b(f);
  }
  o.x = r[0]; o.y = r[1]; o.z = r[2]; o.w = r[3];
  *(ushort4*)(Aout + e0) = o;
}

// ---------------- pack B: [W1 | W2] (K x 768 each) -> bf16 B^T [1536][Kp] ------
__global__ __launch_bounds__(256) void pack_bT(const void* __restrict__ W1,
                                               const void* __restrict__ W2,
                                               unsigned short* __restrict__ Bout,
                                               int K, int Kp, const int* __restrict__ flag) {
  int f32 = flag[0];
  long long gid = (long long)blockIdx.x * 256 + threadIdx.x;
  long long total = (long long)2 * HDIM * Kp / 4;
  if (gid >= total) return;
  long long e0 = gid * 4;
  int n = (int)(e0 / Kp);
  int k = (int)(e0 % Kp);
  const void* W = (n < HDIM) ? W1 : W2;
  int nn = (n < HDIM) ? n : n - HDIM;
  ushort4 o;
  unsigned short r[4];
#pragma unroll
  for (int c = 0; c < 4; ++c) {
    int kk = k + c;
    float f = 0.f;
    if (kk < K) f = ldx(W, (size_t)kk * HDIM + nn, f32);
    r[c] = f2b(f);
  }
  o.x = r[0]; o.y = r[1]; o.z = r[2]; o.w = r[3];
  *(ushort4*)(Bout + e0) = o;
}

// ---------------- MFMA GEMM: C[M,1536] = A[M,Kp] @ B^T[1536,Kp] ----------------
// C cols 0..767 -> C1, 768..1535 -> C2 (both [M][768] bf16).
#define BM 128
#define BN 128
#define BK 64
#define LDK 72   // LDS k-stride (elements): +8 pad -> row stride 144B = 4-bank rotate

__global__ __launch_bounds__(256) void gemm_mfma(const unsigned short* __restrict__ A,
                                                 const unsigned short* __restrict__ Bt,
                                                 __hip_bfloat16* __restrict__ C1,
                                                 __hip_bfloat16* __restrict__ C2,
                                                 int M, int Kp) {
  __shared__ unsigned short Als[BM * LDK];
  __shared__ unsigned short Bls[BN * LDK];
  int t = threadIdx.x;
  int wave = t >> 6, lane = t & 63;
  int quad = lane >> 4, l15 = lane & 15;
  int wrow = (wave & 1) * 64, wcol = (wave >> 1) * 64;
  int m0 = blockIdx.y * BM;
  int n0 = blockIdx.x * BN;
  float4v acc[4][4];
#pragma unroll
  for (int i = 0; i < 4; ++i)
#pragma unroll
    for (int j = 0; j < 4; ++j) acc[i][j] = (float4v){0.f, 0.f, 0.f, 0.f};

  for (int k0 = 0; k0 < Kp; k0 += BK) {
    // stage A tile: 128 rows x 64 k (1024 16B-chunks, 4 per thread)
#pragma unroll
    for (int i = 0; i < 4; ++i) {
      int idx = t + i * 256;
      int row = idx >> 3, c = idx & 7;
      uint4 v = make_uint4(0u, 0u, 0u, 0u);
      int gm = m0 + row;
      if (gm < M) v = *(const uint4*)(A + (size_t)gm * Kp + k0 + c * 8);
      *(uint4*)(Als + row * LDK + c * 8) = v;
    }
    // stage B tile (N rows always valid: 1536 % 128 == 0)
#pragma unroll
    for (int i = 0; i < 4; ++i) {
      int idx = t + i * 256;
      int row = idx >> 3, c = idx & 7;
      uint4 v = *(const uint4*)(Bt + (size_t)(n0 + row) * Kp + k0 + c * 8);
      *(uint4*)(Bls + row * LDK + c * 8) = v;
    }
    __syncthreads();
#pragma unroll
    for (int kk = 0; kk < 2; ++kk) {
      int koff = kk * 32 + quad * 8;
      short8 a[4], b[4];
#pragma unroll
      for (int i = 0; i < 4; ++i)
        a[i] = *(const short8*)(Als + (wrow + i * 16 + l15) * LDK + koff);
#pragma unroll
      for (int j = 0; j < 4; ++j)
        b[j] = *(const short8*)(Bls + (wcol + j * 16 + l15) * LDK + koff);
#pragma unroll
      for (int i = 0; i < 4; ++i)
#pragma unroll
        for (int j = 0; j < 4; ++j)
          acc[i][j] = __builtin_amdgcn_mfma_f32_16x16x32_bf16(a[i], b[j], acc[i][j], 0, 0, 0);
    }
    __syncthreads();
  }

  // epilogue: C/D layout col=lane&15, row=quad*4+reg
  bool second = (n0 >= HDIM);              // block-uniform (768 % 128 == 0)
  __hip_bfloat16* C = second ? C2 : C1;
  int nbase = second ? (n0 - HDIM) : n0;
#pragma unroll
  for (int i = 0; i < 4; ++i) {
    int mrow = m0 + wrow + i * 16 + quad * 4;
#pragma unroll
    for (int j = 0; j < 4; ++j) {
      int n = nbase + wcol + j * 16 + l15;
#pragma unroll
      for (int r = 0; r < 4; ++r) {
        int m = mrow + r;
        if (m < M) C[(size_t)m * HDIM + n] = __float2bfloat16(acc[i][j][r]);
      }
    }
  }
}

// ---------------- CSR build ----------------
__global__ void zero_i32(int* __restrict__ p, int n) {
  int i = blockIdx.x * 256 + threadIdx.x;
  if (i < n) p[i] = 0;
}
__global__ void zero_f32(float* __restrict__ p, int n) {
  int i = blockIdx.x * 256 + threadIdx.x;
  if (i < n) p[i] = 0.f;
}

__global__ void csr_count(const int* __restrict__ dst, int E, int nself, int* __restrict__ cnt) {
  int i = blockIdx.x * 256 + threadIdx.x;
  if (i >= E + nself) return;
  int d = (i < E) ? dst[i] : (i - E);
  atomicAdd(&cnt[d], 1);
}

__global__ __launch_bounds__(256) void scan_excl(const int* __restrict__ cnt,
                                                 int* __restrict__ rowptr, int n) {
  __shared__ int part[256];
  int t = threadIdx.x;
  int strip = (n + 255) / 256;
  int lo = min(t * strip, n), hi = min(lo + strip, n);
  int s = 0;
  for (int i = lo; i < hi; ++i) s += cnt[i];
  part[t] = s;
  __syncthreads();
  if (t == 0) {
    int run = 0;
    for (int i = 0; i < 256; ++i) { int v = part[i]; part[i] = run; run += v; }
  }
  __syncthreads();
  int run = part[t];
  for (int i = lo; i < hi; ++i) { rowptr[i] = run; run += cnt[i]; }
  if (hi == n) rowptr[n] = run;
}

__global__ void csr_fill(const int* __restrict__ src, const int* __restrict__ dst, int E, int nself,
                         const int* __restrict__ rowptr, int* __restrict__ fill,
                         int* __restrict__ eidx) {
  int i = blockIdx.x * 256 + threadIdx.x;
  if (i >= E + nself) return;
  int s, d;
  if (i < E) { s = src[i]; d = dst[i]; } else { s = d = i - E; }
  int pos = rowptr[d] + atomicAdd(&fill[d], 1);
  eidx[pos] = s;
}

// ---------------- fused GAT gather ----------------
// Lane h-mapping: slot c in [0,8): h = 8*lane + c   (row bytes [0,1024), uint4 load)
//                 slot c in [8,12): h = 512 + 4*lane + (c-8)  (row bytes [1024,1536), uint2)
// Both loads 16B/8B aligned, wave-contiguous. Edge loop unrolled x4 for MLP.

__device__ __forceinline__ void fma12(float* acc, uint4 A, uint2 B, float al) {
  unsigned w;
  w = A.x; acc[0]  += al * __uint_as_float(w << 16); acc[1]  += al * __uint_as_float(w & 0xffff0000u);
  w = A.y; acc[2]  += al * __uint_as_float(w << 16); acc[3]  += al * __uint_as_float(w & 0xffff0000u);
  w = A.z; acc[4]  += al * __uint_as_float(w << 16); acc[5]  += al * __uint_as_float(w & 0xffff0000u);
  w = A.w; acc[6]  += al * __uint_as_float(w << 16); acc[7]  += al * __uint_as_float(w & 0xffff0000u);
  w = B.x; acc[8]  += al * __uint_as_float(w << 16); acc[9]  += al * __uint_as_float(w & 0xffff0000u);
  w = B.y; acc[10] += al * __uint_as_float(w << 16); acc[11] += al * __uint_as_float(w & 0xffff0000u);
}

__device__ __forceinline__ float alpha_of(float es4, float edv, float inv) {
  float v = es4 + edv;
  v = (v >= 0.f) ? v : 0.2f * v;
  return __expf(v) * inv;
}

__global__ __launch_bounds__(256) void gat_gather(
    const int* __restrict__ rp1, const int* __restrict__ ei1,
    const __hip_bfloat16* __restrict__ hs1,
    const float* __restrict__ es1, const float* __restrict__ ed1,
    const int* __restrict__ rp2, const int* __restrict__ ei2,
    const __hip_bfloat16* __restrict__ hs2,
    const float* __restrict__ es2, const float* __restrict__ ed2,
    const void* __restrict__ b1, const void* __restrict__ b2,
    int Nd, void* __restrict__ out, size_t base,
    const int* __restrict__ mask, float* __restrict__ parts, int mode,
    const int* __restrict__ flag) {
  int wid = (blockIdx.x * 256 + threadIdx.x) >> 6;
  int lane = threadIdx.x & 63;
  if (wid >= Nd) return;
  int f32 = flag[0];
  float acc[12];
#pragma unroll
  for (int c = 0; c < 12; ++c) {
    int h = (c < 8) ? (8 * lane + c) : (512 + 4 * lane + (c - 8));
    acc[c] = ldx(b1, h, f32) + ldx(b2, h, f32);
  }

#pragma unroll
  for (int rel = 0; rel < 2; ++rel) {
    const int* rp = rel ? rp2 : rp1;
    const int* ei = rel ? ei2 : ei1;
    const unsigned short* hsu = (const unsigned short*)(rel ? hs2 : hs1);
    const float* es = rel ? es2 : es1;
    const float* ed = rel ? ed2 : ed1;
    int lo = rp[wid], hi = rp[wid + 1];
    float edv = ed[4 * (size_t)wid];
    float s = 0.f;
    for (int e = lo + lane; e < hi; e += 64) {
      float v = es[4 * (size_t)ei[e]] + edv;
      v = (v >= 0.f) ? v : 0.2f * v;
      s += __expf(v);
    }
    s = wave_reduce(s);
    float inv = 1.f / (s + 1e-16f);

    int e = lo;
    int p0 = 0, p1 = 0, p2 = 0, p3 = 0;
    if (e + 4 <= hi) { p0 = ei[e]; p1 = ei[e + 1]; p2 = ei[e + 2]; p3 = ei[e + 3]; }
    while (e + 4 <= hi) {
      int sn0 = __builtin_amdgcn_readfirstlane(p0);
      int sn1 = __builtin_amdgcn_readfirstlane(p1);
      int sn2 = __builtin_amdgcn_readfirstlane(p2);
      int sn3 = __builtin_amdgcn_readfirstlane(p3);
      e += 4;
      if (e + 4 <= hi) { p0 = ei[e]; p1 = ei[e + 1]; p2 = ei[e + 2]; p3 = ei[e + 3]; }
      const unsigned short* r0 = hsu + (size_t)sn0 * HDIM;
      const unsigned short* r1 = hsu + (size_t)sn1 * HDIM;
      const unsigned short* r2 = hsu + (size_t)sn2 * HDIM;
      const unsigned short* r3 = hsu + (size_t)sn3 * HDIM;
      uint4 A0 = *(const uint4*)(r0 + 8 * lane);
      uint4 A1 = *(const uint4*)(r1 + 8 * lane);
      uint4 A2 = *(const uint4*)(r2 + 8 * lane);
      uint4 A3 = *(const uint4*)(r3 + 8 * lane);
      uint2 B0 = *(const uint2*)(r0 + 512 + 4 * lane);
      uint2 B1 = *(const uint2*)(r1 + 512 + 4 * lane);
      uint2 B2 = *(const uint2*)(r2 + 512 + 4 * lane);
      uint2 B3 = *(const uint2*)(r3 + 512 + 4 * lane);
      float a0 = alpha_of(es[4 * (size_t)sn0], edv, inv);
      float a1 = alpha_of(es[4 * (size_t)sn1], edv, inv);
      float a2 = alpha_of(es[4 * (size_t)sn2], edv, inv);
      float a3 = alpha_of(es[4 * (size_t)sn3], edv, inv);
      fma12(acc, A0, B0, a0);
      fma12(acc, A1, B1, a1);
      fma12(acc, A2, B2, a2);
      fma12(acc, A3, B3, a3);
    }
    for (; e < hi; ++e) {
      int sn = __builtin_amdgcn_readfirstlane(ei[e]);
      const unsigned short* r0 = hsu + (size_t)sn * HDIM;
      uint4 A0 = *(const uint4*)(r0 + 8 * lane);
      uint2 B0 = *(const uint2*)(r0 + 512 + 4 * lane);
      float a0 = alpha_of(es[4 * (size_t)sn], edv, inv);
      fma12(acc, A0, B0, a0);
    }
  }

  size_t rowbase = base + (size_t)wid * HDIM;
  if (mode == 1) {
#pragma unroll
    for (int c = 0; c < 12; ++c) {
      int h = (c < 8) ? (8 * lane + c) : (512 + 4 * lane + (c - 8));
      float v = acc[c];
      stx(out, rowbase + h, f32, v > 0.f ? v : 0.f);
    }
  } else {
    float cpart = 0.f;
    bool m = mask[wid] != 0;
#pragma unroll
    for (int c = 0; c < 12; ++c) {
      int h = (c < 8) ? (8 * lane + c) : (512 + 4 * lane + (c - 8));
      float v = acc[c];
      v = v > 0.f ? v : 0.f;
      if (m) {
        float d = ldx(out, rowbase + h, f32) - v;
        cpart += d * d;
      }
    }
    cpart = wave_reduce(cpart);
    if (lane == 0 && m) atomicAdd(&parts[wid & 2047], cpart);
  }
}

// ---------------- loss helpers ----------------
__global__ void mask_count(const int* __restrict__ mask, int n, float* __restrict__ cnt) {
  int i = blockIdx.x * 256 + threadIdx.x;
  float v = (i < n && mask[i] != 0) ? 1.f : 0.f;
  v = wave_reduce(v);
  __shared__ float red[4];
  if ((threadIdx.x & 63) == 0) red[threadIdx.x >> 6] = v;
  __syncthreads();
  if (threadIdx.x == 0) atomicAdd(cnt, red[0] + red[1] + red[2] + red[3]);
}

__global__ __launch_bounds__(256) void loss_final(const float* __restrict__ parts,
                                                  const float* __restrict__ cnts,
                                                  void* __restrict__ out, size_t off,
                                                  const int* __restrict__ flag) {
  float a = 0.f, b = 0.f;
  for (int i = threadIdx.x; i < 2048; i += 256) { a += parts[i]; b += parts[2048 + i]; }
  a = wave_reduce(a);
  b = wave_reduce(b);
  __shared__ float ra[4], rb[4];
  if ((threadIdx.x & 63) == 0) { ra[threadIdx.x >> 6] = a; rb[threadIdx.x >> 6] = b; }
  __syncthreads();
  if (threadIdx.x == 0) {
    float sd = ra[0] + ra[1] + ra[2] + ra[3];
    float st = rb[0] + rb[1] + rb[2] + rb[3];
    float loss = sd / (cnts[0] * (float)HDIM + 1e-16f) + st / (cnts[1] * (float)HDIM + 1e-16f);
    stx(out, off, flag[0], loss);
  }
}

// ---------------- host ----------------

extern "C" void kernel_launch(void* const* d_in, const int* in_sizes, int n_in,
                              void* d_out, int out_size, void* d_ws, size_t ws_size,
                              hipStream_t stream) {
  const void* drug_x    = d_in[0];
  const void* target_x  = d_in[1];
  const int* dd_src = (const int*)d_in[2];
  const int* dd_dst = (const int*)d_in[3];
  const int* dt_src = (const int*)d_in[4];
  const int* dt_dst = (const int*)d_in[5];
  const int* tt_src = (const int*)d_in[6];
  const int* tt_dst = (const int*)d_in[7];
  const int* drug_mask   = (const int*)d_in[8];
  const int* target_mask = (const int*)d_in[9];
  const void* mask_drug   = d_in[10];
  const void* mask_target = d_in[11];
  const void* Wsrc_dd = d_in[12]; const void* Wdst_dd = d_in[13];
  const void* asrc_dd = d_in[14]; const void* adst_dd = d_in[15];
  const void* b_dd    = d_in[16];
  const void* Wsrc_dt = d_in[17]; const void* Wdst_dt = d_in[18];
  const void* asrc_dt = d_in[19]; const void* adst_dt = d_in[20];
  const void* b_dt    = d_in[21];
  const void* Wsrc_rv = d_in[22]; const void* Wdst_rv = d_in[23];
  const void* asrc_rv = d_in[24]; const void* adst_rv = d_in[25];
  const void* b_rv    = d_in[26];
  const void* Wsrc_tt = d_in[27]; const void* Wdst_tt = d_in[28];
  const void* asrc_tt = d_in[29]; const void* adst_tt = d_in[30];
  const void* b_tt    = d_in[31];

  char* p = (char*)d_ws;
  auto alloc = [&](size_t bytes) -> void* {
    void* r = (void*)p;
    p += (bytes + 255) & ~(size_t)255;
    return r;
  };
  __hip_bfloat16* hs_dd = (__hip_bfloat16*)alloc((size_t)ND * HDIM * 2);
  __hip_bfloat16* hs_rv = (__hip_bfloat16*)alloc((size_t)NT * HDIM * 2);
  __hip_bfloat16* hs_dt = (__hip_bfloat16*)alloc((size_t)ND * HDIM * 2);
  __hip_bfloat16* hs_tt = (__hip_bfloat16*)alloc((size_t)NT * HDIM * 2);
  unsigned short* Ad = (unsigned short*)alloc((size_t)ND * KPD * 2);
  unsigned short* At = (unsigned short*)alloc((size_t)NT * KPT * 2);
  unsigned short* Bd = (unsigned short*)alloc((size_t)2 * HDIM * KPD * 2);
  unsigned short* Bt = (unsigned short*)alloc((size_t)2 * HDIM * KPT * 2);
  float* dvec = (float*)alloc((size_t)ND * 4 * 4);   // {es_dd, ed_dd, ed_rv, es_dt}
  float* tvec = (float*)alloc((size_t)NT * 4 * 4);   // {es_rv, ed_dt, es_tt, ed_tt}
  int* rp_dd = (int*)alloc((size_t)(ND + 1) * 4);
  int* rp_rv = (int*)alloc((size_t)(ND + 1) * 4);
  int* rp_dt = (int*)alloc((size_t)(NT + 1) * 4);
  int* rp_tt = (int*)alloc((size_t)(NT + 1) * 4);
  int* ei_dd = (int*)alloc((size_t)(EDD + ND) * 4);
  int* ei_rv = (int*)alloc((size_t)EDT * 4);
  int* ei_dt = (int*)alloc((size_t)EDT * 4);
  int* ei_tt = (int*)alloc((size_t)(ETT + NT) * 4);
  int* cnt   = (int*)alloc((size_t)ND * 4);
  int* fill  = (int*)alloc((size_t)ND * 4);
  float* vaD = (float*)alloc((size_t)4 * FD * 4);
  float* vaT = (float*)alloc((size_t)4 * FT * 4);
  float* parts = (float*)alloc((size_t)(4096 + 2) * 4);
  float* cnts  = parts + 4096;
  int*   flag  = (int*)alloc(256);

  // 1) dtype sniff
  sniff<<<1, 256, 0, stream>>>(drug_x, flag);

  // 2) zero loss partials + mask counters
  zero_f32<<<(4098 + 255) / 256, 256, 0, stream>>>(parts, 4098);
  mask_count<<<(ND + 255) / 256, 256, 0, stream>>>(drug_mask, ND, cnts + 0);
  mask_count<<<(NT + 255) / 256, 256, 0, stream>>>(target_mask, NT, cnts + 1);

  // 3) va vectors
  struct { const void* W; const void* a; int fin; float* out; } vas[8] = {
    {Wsrc_dd, asrc_dd, FD, vaD + 0 * FD}, {Wdst_dd, adst_dd, FD, vaD + 1 * FD},
    {Wdst_rv, adst_rv, FD, vaD + 2 * FD}, {Wsrc_dt, asrc_dt, FD, vaD + 3 * FD},
    {Wsrc_rv, asrc_rv, FT, vaT + 0 * FT}, {Wdst_dt, adst_dt, FT, vaT + 1 * FT},
    {Wsrc_tt, asrc_tt, FT, vaT + 2 * FT}, {Wdst_tt, adst_tt, FT, vaT + 3 * FT},
  };
  for (int i = 0; i < 8; ++i)
    wa_dot<<<(vas[i].fin * 64 + 255) / 256, 256, 0, stream>>>(vas[i].W, vas[i].a,
                                                              vas[i].out, vas[i].fin, flag);

  // 4) pack weights (once; same for both layers): drug B = [Wsrc_dd | Wsrc_dt],
  //    target B = [Wsrc_rv | Wsrc_tt]
  {
    long long tb = (long long)2 * HDIM * KPD / 4;
    pack_bT<<<(int)((tb + 255) / 256), 256, 0, stream>>>(Wsrc_dd, Wsrc_dt, Bd, FD, KPD, flag);
    tb = (long long)2 * HDIM * KPT / 4;
    pack_bT<<<(int)((tb + 255) / 256), 256, 0, stream>>>(Wsrc_rv, Wsrc_tt, Bt, FT, KPT, flag);
  }

  // 5) CSR build (once; reused by both layers)
  auto build_csr = [&](const int* srcI, const int* dstI, int E, int nself, int Nd,
                       int* rowptr, int* eidx) {
    int ET = E + nself;
    zero_i32<<<(Nd + 255) / 256, 256, 0, stream>>>(cnt, Nd);
    csr_count<<<(ET + 255) / 256, 256, 0, stream>>>(dstI, E, nself, cnt);
    scan_excl<<<1, 256, 0, stream>>>(cnt, rowptr, Nd);
    zero_i32<<<(Nd + 255) / 256, 256, 0, stream>>>(fill, Nd);
    csr_fill<<<(ET + 255) / 256, 256, 0, stream>>>(srcI, dstI, E, nself, rowptr, fill, eidx);
  };
  build_csr(dd_src, dd_dst, EDD, ND, ND, rp_dd, ei_dd);
  build_csr(dt_dst, dt_src, EDT, 0,  ND, rp_rv, ei_rv);
  build_csr(dt_src, dt_dst, EDT, 0,  NT, rp_dt, ei_dt);
  build_csr(tt_src, tt_dst, ETT, NT, NT, rp_tt, ei_tt);

  size_t baseT = (size_t)ND * HDIM;
  size_t baseL = baseT + (size_t)NT * HDIM;

  // 6) per-layer pipeline
  auto run_layer = [&](const int* mD, const int* mT, int mode) {
    row_dot4<<<(ND + 3) / 4, 256, 0, stream>>>(drug_x, mD, mask_drug, vaD, dvec, ND, FD, flag);
    row_dot4<<<(NT + 3) / 4, 256, 0, stream>>>(target_x, mT, mask_target, vaT, tvec, NT, FT, flag);
    {
      long long ta = (long long)ND * KPD / 4;
      pack_a<<<(int)((ta + 255) / 256), 256, 0, stream>>>(drug_x, mD, mask_drug, Ad, ND, FD, KPD, flag);
      ta = (long long)NT * KPT / 4;
      pack_a<<<(int)((ta + 255) / 256), 256, 0, stream>>>(target_x, mT, mask_target, At, NT, FT, KPT, flag);
    }
    dim3 gD(2 * HDIM / BN, (ND + BM - 1) / BM);
    dim3 gT(2 * HDIM / BN, (NT + BM - 1) / BM);
    gemm_mfma<<<gD, 256, 0, stream>>>(Ad, Bd, hs_dd, hs_dt, ND, KPD);
    gemm_mfma<<<gT, 256, 0, stream>>>(At, Bt, hs_rv, hs_tt, NT, KPT);
    // drugs: rel1 = dd (es=dvec.0, ed=dvec.1), rel2 = rv (es=tvec.0, ed=dvec.2)
    gat_gather<<<(ND + 3) / 4, 256, 0, stream>>>(
        rp_dd, ei_dd, hs_dd, dvec + 0, dvec + 1,
        rp_rv, ei_rv, hs_rv, tvec + 0, dvec + 2,
        b_dd, b_rv, ND, d_out, 0, drug_mask, parts, mode, flag);
    // targets: rel1 = dt (es=dvec.3, ed=tvec.1), rel2 = tt (es=tvec.2, ed=tvec.3)
    gat_gather<<<(NT + 3) / 4, 256, 0, stream>>>(
        rp_dt, ei_dt, hs_dt, dvec + 3, tvec + 1,
        rp_tt, ei_tt, hs_tt, tvec + 2, tvec + 3,
        b_dt, b_tt, NT, d_out, baseT, target_mask, parts + 2048, mode, flag);
  };

  run_layer(nullptr, nullptr, 1);          // layer 1
  run_layer(drug_mask, target_mask, 2);    // layer 2 + fused loss
  loss_final<<<1, 256, 0, stream>>>(parts, cnts, d_out, baseL, flag);
}

// Round 2
// 1556.843 us; speedup vs baseline: 1.0212x; 1.0212x over previous
//
#include <hip/hip_runtime.h>
#include <hip/hip_bf16.h>

#define ND 30000
#define NT 15000
#define FD 200
#define FT 570
#define HDIM 768
#define EDD 300000
#define EDT 400000
#define ETT 200000

#define KPD 256   // FD padded to x64
#define KPT 576   // FT padded to x64

#define NSLICE 3      // HDIM / 256 column slices for the gather
#define SLICE_H 256   // 256 h per slice = 512B/row-slice = uint2 per lane

typedef __attribute__((ext_vector_type(8))) short short8;
typedef __attribute__((ext_vector_type(4))) float float4v;

// ---------------- dtype-adaptive load/store ----------------
// flag[0]: 0 = harness float tensors are bf16, 1 = fp32.

__device__ __forceinline__ float ldx(const void* p, size_t i, int f32) {
  return f32 ? ((const float*)p)[i]
             : __bfloat162float(((const __hip_bfloat16*)p)[i]);
}
__device__ __forceinline__ void stx(void* p, size_t i, int f32, float v) {
  if (f32) ((float*)p)[i] = v;
  else     ((__hip_bfloat16*)p)[i] = __float2bfloat16(v);
}
__device__ __forceinline__ float b2f(unsigned short u) {
  return __uint_as_float(((unsigned)u) << 16);
}
__device__ __forceinline__ unsigned short f2b(float f) {
  __hip_bfloat16 h = __float2bfloat16(f);
  return *(unsigned short*)&h;
}

__device__ __forceinline__ float wave_reduce(float v) {
#pragma unroll
  for (int off = 32; off > 0; off >>= 1) v += __shfl_xor(v, off, 64);
  return v;
}

// ---------------- dtype sniffer ----------------
__global__ void sniff(const void* x, int* flag) {
  int t = threadIdx.x;
  float cnt = 0.f;
  for (int i = t; i < 8192; i += 256) {
    float v = __bfloat162float(((const __hip_bfloat16*)x)[i]);
    if (!(fabsf(v) < 100.f)) cnt += 1.f;  // true for NaN too
  }
  cnt = wave_reduce(cnt);
  __shared__ float red[4];
  if ((t & 63) == 0) red[t >> 6] = cnt;
  __syncthreads();
  if (t == 0) flag[0] = (red[0] + red[1] + red[2] + red[3] > 256.f) ? 1 : 0;
}

// ---------------- va[k] = sum_h W[k,h]*a[h], one wave per k ----------------
__global__ __launch_bounds__(256) void wa_dot(const void* __restrict__ W, const void* __restrict__ a,
                                              float* __restrict__ outv, int fin,
                                              const int* __restrict__ flag) {
  int f32 = flag[0];
  int k = (blockIdx.x * 256 + threadIdx.x) >> 6;
  int lane = threadIdx.x & 63;
  if (k >= fin) return;
  float acc = 0.f;
  for (int h = lane; h < HDIM; h += 64)
    acc += ldx(W, (size_t)k * HDIM + h, f32) * ldx(a, h, f32);
  acc = wave_reduce(acc);
  if (lane == 0) outv[k] = acc;
}

// ---------- 4 dots per row (shared x read), one wave per row ----------
__global__ __launch_bounds__(256) void row_dot4(const void* __restrict__ x,
                                                const int* __restrict__ mask,
                                                const void* __restrict__ tok,
                                                const float* __restrict__ va,
                                                float* __restrict__ outv, int N, int K,
                                                const int* __restrict__ flag) {
  int f32 = flag[0];
  int row = (blockIdx.x * 256 + threadIdx.x) >> 6;
  int lane = threadIdx.x & 63;
  if (row >= N) return;
  bool msk = (mask != nullptr) && (mask[row] != 0);
  float a0 = 0.f, a1 = 0.f, a2 = 0.f, a3 = 0.f;
  for (int k = lane; k < K; k += 64) {
    float v = msk ? ldx(tok, k, f32) : ldx(x, (size_t)row * K + k, f32);
    a0 += v * va[k];
    a1 += v * va[K + k];
    a2 += v * va[2 * K + k];
    a3 += v * va[3 * K + k];
  }
  a0 = wave_reduce(a0); a1 = wave_reduce(a1);
  a2 = wave_reduce(a2); a3 = wave_reduce(a3);
  if (lane == 0) {
    float* o = outv + (size_t)row * 4;
    o[0] = a0; o[1] = a1; o[2] = a2; o[3] = a3;
  }
}

// ---------------- pack A: x_eff -> bf16 [M][Kp], zero-padded K ----------------
__global__ __launch_bounds__(256) void pack_a(const void* __restrict__ x,
                                              const int* __restrict__ mask,
                                              const void* __restrict__ tok,
                                              unsigned short* __restrict__ Aout,
                                              int M, int K, int Kp,
                                              const int* __restrict__ flag) {
  int f32 = flag[0];
  long long gid = (long long)blockIdx.x * 256 + threadIdx.x;
  long long total = (long long)M * Kp / 4;
  if (gid >= total) return;
  long long e0 = gid * 4;
  int row = (int)(e0 / Kp);
  int k = (int)(e0 % Kp);
  bool msk = (mask != nullptr) && (mask[row] != 0);
  ushort4 o;
  unsigned short r[4];
#pragma unroll
  for (int c = 0; c < 4; ++c) {
    int kk = k + c;
    float f = 0.f;
    if (kk < K) f = msk ? ldx(tok, kk, f32) : ldx(x, (size_t)row * K + kk, f32);
    r[c] = f2b(f);
  }
  o.x = r[0]; o.y = r[1]; o.z = r[2]; o.w = r[3];
  *(ushort4*)(Aout + e0) = o;
}

// ---------------- pack B: [W1 | W2] (K x 768 each) -> bf16 B^T [1536][Kp] ------
__global__ __launch_bounds__(256) void pack_bT(const void* __restrict__ W1,
                                               const void* __restrict__ W2,
                                               unsigned short* __restrict__ Bout,
                                               int K, int Kp, const int* __restrict__ flag) {
  int f32 = flag[0];
  long long gid = (long long)blockIdx.x * 256 + threadIdx.x;
  long long total = (long long)2 * HDIM * Kp / 4;
  if (gid >= total) return;
  long long e0 = gid * 4;
  int n = (int)(e0 / Kp);
  int k = (int)(e0 % Kp);
  const void* W = (n < HDIM) ? W1 : W2;
  int nn = (n < HDIM) ? n : n - HDIM;
  ushort4 o;
  unsigned short r[4];
#pragma unroll
  for (int c = 0; c < 4; ++c) {
    int kk = k + c;
    float f = 0.f;
    if (kk < K) f = ldx(W, (size_t)kk * HDIM + nn, f32);
    r[c] = f2b(f);
  }
  o.x = r[0]; o.y = r[1]; o.z = r[2]; o.w = r[3];
  *(ushort4*)(Bout + e0) = o;
}

// ---------------- MFMA GEMM: C[M,1536] = A[M,Kp] @ B^T[1536,Kp] ----------------
// C cols 0..767 -> C1, 768..1535 -> C2 (both [M][768] bf16).
#define BM 128
#define BN 128
#define BK 64
#define LDK 72   // LDS k-stride (elements): +8 pad -> row stride 144B = 4-bank rotate

__global__ __launch_bounds__(256) void gemm_mfma(const unsigned short* __restrict__ A,
                                                 const unsigned short* __restrict__ Bt,
                                                 __hip_bfloat16* __restrict__ C1,
                                                 __hip_bfloat16* __restrict__ C2,
                                                 int M, int Kp) {
  __shared__ unsigned short Als[BM * LDK];
  __shared__ unsigned short Bls[BN * LDK];
  int t = threadIdx.x;
  int wave = t >> 6, lane = t & 63;
  int quad = lane >> 4, l15 = lane & 15;
  int wrow = (wave & 1) * 64, wcol = (wave >> 1) * 64;
  int m0 = blockIdx.y * BM;
  int n0 = blockIdx.x * BN;
  float4v acc[4][4];
#pragma unroll
  for (int i = 0; i < 4; ++i)
#pragma unroll
    for (int j = 0; j < 4; ++j) acc[i][j] = (float4v){0.f, 0.f, 0.f, 0.f};

  for (int k0 = 0; k0 < Kp; k0 += BK) {
    // stage A tile: 128 rows x 64 k (1024 16B-chunks, 4 per thread)
#pragma unroll
    for (int i = 0; i < 4; ++i) {
      int idx = t + i * 256;
      int row = idx >> 3, c = idx & 7;
      uint4 v = make_uint4(0u, 0u, 0u, 0u);
      int gm = m0 + row;
      if (gm < M) v = *(const uint4*)(A + (size_t)gm * Kp + k0 + c * 8);
      *(uint4*)(Als + row * LDK + c * 8) = v;
    }
    // stage B tile (N rows always valid: 1536 % 128 == 0)
#pragma unroll
    for (int i = 0; i < 4; ++i) {
      int idx = t + i * 256;
      int row = idx >> 3, c = idx & 7;
      uint4 v = *(const uint4*)(Bt + (size_t)(n0 + row) * Kp + k0 + c * 8);
      *(uint4*)(Bls + row * LDK + c * 8) = v;
    }
    __syncthreads();
#pragma unroll
    for (int kk = 0; kk < 2; ++kk) {
      int koff = kk * 32 + quad * 8;
      short8 a[4], b[4];
#pragma unroll
      for (int i = 0; i < 4; ++i)
        a[i] = *(const short8*)(Als + (wrow + i * 16 + l15) * LDK + koff);
#pragma unroll
      for (int j = 0; j < 4; ++j)
        b[j] = *(const short8*)(Bls + (wcol + j * 16 + l15) * LDK + koff);
#pragma unroll
      for (int i = 0; i < 4; ++i)
#pragma unroll
        for (int j = 0; j < 4; ++j)
          acc[i][j] = __builtin_amdgcn_mfma_f32_16x16x32_bf16(a[i], b[j], acc[i][j], 0, 0, 0);
    }
    __syncthreads();
  }

  // epilogue: C/D layout col=lane&15, row=quad*4+reg
  bool second = (n0 >= HDIM);              // block-uniform (768 % 128 == 0)
  __hip_bfloat16* C = second ? C2 : C1;
  int nbase = second ? (n0 - HDIM) : n0;
#pragma unroll
  for (int i = 0; i < 4; ++i) {
    int mrow = m0 + wrow + i * 16 + quad * 4;
#pragma unroll
    for (int j = 0; j < 4; ++j) {
      int n = nbase + wcol + j * 16 + l15;
#pragma unroll
      for (int r = 0; r < 4; ++r) {
        int m = mrow + r;
        if (m < M) C[(size_t)m * HDIM + n] = __float2bfloat16(acc[i][j][r]);
      }
    }
  }
}

// ---------------- CSR build ----------------
__global__ void zero_i32(int* __restrict__ p, int n) {
  int i = blockIdx.x * 256 + threadIdx.x;
  if (i < n) p[i] = 0;
}
__global__ void zero_f32(float* __restrict__ p, int n) {
  int i = blockIdx.x * 256 + threadIdx.x;
  if (i < n) p[i] = 0.f;
}

__global__ void csr_count(const int* __restrict__ dst, int E, int nself, int* __restrict__ cnt) {
  int i = blockIdx.x * 256 + threadIdx.x;
  if (i >= E + nself) return;
  int d = (i < E) ? dst[i] : (i - E);
  atomicAdd(&cnt[d], 1);
}

__global__ __launch_bounds__(256) void scan_excl(const int* __restrict__ cnt,
                                                 int* __restrict__ rowptr, int n) {
  __shared__ int part[256];
  int t = threadIdx.x;
  int strip = (n + 255) / 256;
  int lo = min(t * strip, n), hi = min(lo + strip, n);
  int s = 0;
  for (int i = lo; i < hi; ++i) s += cnt[i];
  part[t] = s;
  __syncthreads();
  if (t == 0) {
    int run = 0;
    for (int i = 0; i < 256; ++i) { int v = part[i]; part[i] = run; run += v; }
  }
  __syncthreads();
  int run = part[t];
  for (int i = lo; i < hi; ++i) { rowptr[i] = run; run += cnt[i]; }
  if (hi == n) rowptr[n] = run;
}

__global__ void csr_fill(const int* __restrict__ src, const int* __restrict__ dst, int E, int nself,
                         const int* __restrict__ rowptr, int* __restrict__ fill,
                         int* __restrict__ eidx) {
  int i = blockIdx.x * 256 + threadIdx.x;
  if (i >= E + nself) return;
  int s, d;
  if (i < E) { s = src[i]; d = dst[i]; } else { s = d = i - E; }
  int pos = rowptr[d] + atomicAdd(&fill[d], 1);
  eidx[pos] = s;
}

// ---------------- fused GAT gather, h-sliced ----------------
// Grid is 1-D, slice-major: block b -> slice = b / nb, node-block = b % nb.
// Each pass touches only SLICE_H=256 columns (512B/row) so the per-pass hs
// working set (23MB) has 3x better L2 residency than the full 69MB.
// Lane h-mapping within slice: h = hbase + 4*lane + c, c in [0,4) (uint2/lane).

__device__ __forceinline__ void fma4(float* acc, uint2 A, float al) {
  unsigned w;
  w = A.x; acc[0] += al * __uint_as_float(w << 16); acc[1] += al * __uint_as_float(w & 0xffff0000u);
  w = A.y; acc[2] += al * __uint_as_float(w << 16); acc[3] += al * __uint_as_float(w & 0xffff0000u);
}

__device__ __forceinline__ float alpha_of(float es4, float edv, float inv) {
  float v = es4 + edv;
  v = (v >= 0.f) ? v : 0.2f * v;
  return __expf(v) * inv;
}

__global__ __launch_bounds__(256) void gat_gather(
    const int* __restrict__ rp1, const int* __restrict__ ei1,
    const __hip_bfloat16* __restrict__ hs1,
    const float* __restrict__ es1, const float* __restrict__ ed1,
    const int* __restrict__ rp2, const int* __restrict__ ei2,
    const __hip_bfloat16* __restrict__ hs2,
    const float* __restrict__ es2, const float* __restrict__ ed2,
    const void* __restrict__ b1, const void* __restrict__ b2,
    int Nd, int nb, void* __restrict__ out, size_t base,
    const int* __restrict__ mask, float* __restrict__ parts, int mode,
    const int* __restrict__ flag) {
  int slice = blockIdx.x / nb;
  int blk = blockIdx.x - slice * nb;
  int wid = blk * 4 + (threadIdx.x >> 6);
  int lane = threadIdx.x & 63;
  if (wid >= Nd) return;
  int f32 = flag[0];
  int hoff = slice * SLICE_H + 4 * lane;  // this lane's 4 h-columns
  float acc[4];
#pragma unroll
  for (int c = 0; c < 4; ++c)
    acc[c] = ldx(b1, hoff + c, f32) + ldx(b2, hoff + c, f32);

#pragma unroll
  for (int rel = 0; rel < 2; ++rel) {
    const int* rp = rel ? rp2 : rp1;
    const int* ei = rel ? ei2 : ei1;
    const unsigned short* hsu = (const unsigned short*)(rel ? hs2 : hs1);
    const float* es = rel ? es2 : es1;
    const float* ed = rel ? ed2 : ed1;
    int lo = rp[wid], hi = rp[wid + 1];
    float edv = ed[4 * (size_t)wid];
    float s = 0.f;
    for (int e = lo + lane; e < hi; e += 64) {
      float v = es[4 * (size_t)ei[e]] + edv;
      v = (v >= 0.f) ? v : 0.2f * v;
      s += __expf(v);
    }
    s = wave_reduce(s);
    float inv = 1.f / (s + 1e-16f);

    int e = lo;
    int p0 = 0, p1 = 0, p2 = 0, p3 = 0;
    if (e + 4 <= hi) { p0 = ei[e]; p1 = ei[e + 1]; p2 = ei[e + 2]; p3 = ei[e + 3]; }
    while (e + 4 <= hi) {
      int sn0 = __builtin_amdgcn_readfirstlane(p0);
      int sn1 = __builtin_amdgcn_readfirstlane(p1);
      int sn2 = __builtin_amdgcn_readfirstlane(p2);
      int sn3 = __builtin_amdgcn_readfirstlane(p3);
      e += 4;
      if (e + 4 <= hi) { p0 = ei[e]; p1 = ei[e + 1]; p2 = ei[e + 2]; p3 = ei[e + 3]; }
      uint2 A0 = *(const uint2*)(hsu + (size_t)sn0 * HDIM + hoff);
      uint2 A1 = *(const uint2*)(hsu + (size_t)sn1 * HDIM + hoff);
      uint2 A2 = *(const uint2*)(hsu + (size_t)sn2 * HDIM + hoff);
      uint2 A3 = *(const uint2*)(hsu + (size_t)sn3 * HDIM + hoff);
      float a0 = alpha_of(es[4 * (size_t)sn0], edv, inv);
      float a1 = alpha_of(es[4 * (size_t)sn1], edv, inv);
      float a2 = alpha_of(es[4 * (size_t)sn2], edv, inv);
      float a3 = alpha_of(es[4 * (size_t)sn3], edv, inv);
      fma4(acc, A0, a0);
      fma4(acc, A1, a1);
      fma4(acc, A2, a2);
      fma4(acc, A3, a3);
    }
    for (; e < hi; ++e) {
      int sn = __builtin_amdgcn_readfirstlane(ei[e]);
      uint2 A0 = *(const uint2*)(hsu + (size_t)sn * HDIM + hoff);
      float a0 = alpha_of(es[4 * (size_t)sn], edv, inv);
      fma4(acc, A0, a0);
    }
  }

  size_t rowbase = base + (size_t)wid * HDIM + hoff;
  if (mode == 1) {
#pragma unroll
    for (int c = 0; c < 4; ++c) {
      float v = acc[c];
      stx(out, rowbase + c, f32, v > 0.f ? v : 0.f);
    }
  } else {
    float cpart = 0.f;
    bool m = mask[wid] != 0;
#pragma unroll
    for (int c = 0; c < 4; ++c) {
      float v = acc[c];
      v = v > 0.f ? v : 0.f;
      if (m) {
        float d = ldx(out, rowbase + c, f32) - v;
        cpart += d * d;
      }
    }
    cpart = wave_reduce(cpart);
    if (lane == 0 && m) atomicAdd(&parts[wid & 2047], cpart);
  }
}

// ---------------- loss helpers ----------------
__global__ void mask_count(const int* __restrict__ mask, int n, float* __restrict__ cnt) {
  int i = blockIdx.x * 256 + threadIdx.x;
  float v = (i < n && mask[i] != 0) ? 1.f : 0.f;
  v = wave_reduce(v);
  __shared__ float red[4];
  if ((threadIdx.x & 63) == 0) red[threadIdx.x >> 6] = v;
  __syncthreads();
  if (threadIdx.x == 0) atomicAdd(cnt, red[0] + red[1] + red[2] + red[3]);
}

__global__ __launch_bounds__(256) void loss_final(const float* __restrict__ parts,
                                                  const float* __restrict__ cnts,
                                                  void* __restrict__ out, size_t off,
                                                  const int* __restrict__ flag) {
  float a = 0.f, b = 0.f;
  for (int i = threadIdx.x; i < 2048; i += 256) { a += parts[i]; b += parts[2048 + i]; }
  a = wave_reduce(a);
  b = wave_reduce(b);
  __shared__ float ra[4], rb[4];
  if ((threadIdx.x & 63) == 0) { ra[threadIdx.x >> 6] = a; rb[threadIdx.x >> 6] = b; }
  __syncthreads();
  if (threadIdx.x == 0) {
    float sd = ra[0] + ra[1] + ra[2] + ra[3];
    float st = rb[0] + rb[1] + rb[2] + rb[3];
    float loss = sd / (cnts[0] * (float)HDIM + 1e-16f) + st / (cnts[1] * (float)HDIM + 1e-16f);
    stx(out, off, flag[0], loss);
  }
}

// ---------------- host ----------------

extern "C" void kernel_launch(void* const* d_in, const int* in_sizes, int n_in,
                              void* d_out, int out_size, void* d_ws, size_t ws_size,
                              hipStream_t stream) {
  const void* drug_x    = d_in[0];
  const void* target_x  = d_in[1];
  const int* dd_src = (const int*)d_in[2];
  const int* dd_dst = (const int*)d_in[3];
  const int* dt_src = (const int*)d_in[4];
  const int* dt_dst = (const int*)d_in[5];
  const int* tt_src = (const int*)d_in[6];
  const int* tt_dst = (const int*)d_in[7];
  const int* drug_mask   = (const int*)d_in[8];
  const int* target_mask = (const int*)d_in[9];
  const void* mask_drug   = d_in[10];
  const void* mask_target = d_in[11];
  const void* Wsrc_dd = d_in[12]; const void* Wdst_dd = d_in[13];
  const void* asrc_dd = d_in[14]; const void* adst_dd = d_in[15];
  const void* b_dd    = d_in[16];
  const void* Wsrc_dt = d_in[17]; const void* Wdst_dt = d_in[18];
  const void* asrc_dt = d_in[19]; const void* adst_dt = d_in[20];
  const void* b_dt    = d_in[21];
  const void* Wsrc_rv = d_in[22]; const void* Wdst_rv = d_in[23];
  const void* asrc_rv = d_in[24]; const void* adst_rv = d_in[25];
  const void* b_rv    = d_in[26];
  const void* Wsrc_tt = d_in[27]; const void* Wdst_tt = d_in[28];
  const void* asrc_tt = d_in[29]; const void* adst_tt = d_in[30];
  const void* b_tt    = d_in[31];

  char* p = (char*)d_ws;
  auto alloc = [&](size_t bytes) -> void* {
    void* r = (void*)p;
    p += (bytes + 255) & ~(size_t)255;
    return r;
  };
  __hip_bfloat16* hs_dd = (__hip_bfloat16*)alloc((size_t)ND * HDIM * 2);
  __hip_bfloat16* hs_rv = (__hip_bfloat16*)alloc((size_t)NT * HDIM * 2);
  __hip_bfloat16* hs_dt = (__hip_bfloat16*)alloc((size_t)ND * HDIM * 2);
  __hip_bfloat16* hs_tt = (__hip_bfloat16*)alloc((size_t)NT * HDIM * 2);
  unsigned short* Ad = (unsigned short*)alloc((size_t)ND * KPD * 2);
  unsigned short* At = (unsigned short*)alloc((size_t)NT * KPT * 2);
  unsigned short* Bd = (unsigned short*)alloc((size_t)2 * HDIM * KPD * 2);
  unsigned short* Bt = (unsigned short*)alloc((size_t)2 * HDIM * KPT * 2);
  float* dvec = (float*)alloc((size_t)ND * 4 * 4);   // {es_dd, ed_dd, ed_rv, es_dt}
  float* tvec = (float*)alloc((size_t)NT * 4 * 4);   // {es_rv, ed_dt, es_tt, ed_tt}
  int* rp_dd = (int*)alloc((size_t)(ND + 1) * 4);
  int* rp_rv = (int*)alloc((size_t)(ND + 1) * 4);
  int* rp_dt = (int*)alloc((size_t)(NT + 1) * 4);
  int* rp_tt = (int*)alloc((size_t)(NT + 1) * 4);
  int* ei_dd = (int*)alloc((size_t)(EDD + ND) * 4);
  int* ei_rv = (int*)alloc((size_t)EDT * 4);
  int* ei_dt = (int*)alloc((size_t)EDT * 4);
  int* ei_tt = (int*)alloc((size_t)(ETT + NT) * 4);
  int* cnt   = (int*)alloc((size_t)ND * 4);
  int* fill  = (int*)alloc((size_t)ND * 4);
  float* vaD = (float*)alloc((size_t)4 * FD * 4);
  float* vaT = (float*)alloc((size_t)4 * FT * 4);
  float* parts = (float*)alloc((size_t)(4096 + 2) * 4);
  float* cnts  = parts + 4096;
  int*   flag  = (int*)alloc(256);

  // 1) dtype sniff
  sniff<<<1, 256, 0, stream>>>(drug_x, flag);

  // 2) zero loss partials + mask counters
  zero_f32<<<(4098 + 255) / 256, 256, 0, stream>>>(parts, 4098);
  mask_count<<<(ND + 255) / 256, 256, 0, stream>>>(drug_mask, ND, cnts + 0);
  mask_count<<<(NT + 255) / 256, 256, 0, stream>>>(target_mask, NT, cnts + 1);

  // 3) va vectors
  struct { const void* W; const void* a; int fin; float* out; } vas[8] = {
    {Wsrc_dd, asrc_dd, FD, vaD + 0 * FD}, {Wdst_dd, adst_dd, FD, vaD + 1 * FD},
    {Wdst_rv, adst_rv, FD, vaD + 2 * FD}, {Wsrc_dt, asrc_dt, FD, vaD + 3 * FD},
    {Wsrc_rv, asrc_rv, FT, vaT + 0 * FT}, {Wdst_dt, adst_dt, FT, vaT + 1 * FT},
    {Wsrc_tt, asrc_tt, FT, vaT + 2 * FT}, {Wdst_tt, adst_tt, FT, vaT + 3 * FT},
  };
  for (int i = 0; i < 8; ++i)
    wa_dot<<<(vas[i].fin * 64 + 255) / 256, 256, 0, stream>>>(vas[i].W, vas[i].a,
                                                              vas[i].out, vas[i].fin, flag);

  // 4) pack weights (once; same for both layers): drug B = [Wsrc_dd | Wsrc_dt],
  //    target B = [Wsrc_rv | Wsrc_tt]
  {
    long long tb = (long long)2 * HDIM * KPD / 4;
    pack_bT<<<(int)((tb + 255) / 256), 256, 0, stream>>>(Wsrc_dd, Wsrc_dt, Bd, FD, KPD, flag);
    tb = (long long)2 * HDIM * KPT / 4;
    pack_bT<<<(int)((tb + 255) / 256), 256, 0, stream>>>(Wsrc_rv, Wsrc_tt, Bt, FT, KPT, flag);
  }

  // 5) CSR build (once; reused by both layers)
  auto build_csr = [&](const int* srcI, const int* dstI, int E, int nself, int Nd,
                       int* rowptr, int* eidx) {
    int ET = E + nself;
    zero_i32<<<(Nd + 255) / 256, 256, 0, stream>>>(cnt, Nd);
    csr_count<<<(ET + 255) / 256, 256, 0, stream>>>(dstI, E, nself, cnt);
    scan_excl<<<1, 256, 0, stream>>>(cnt, rowptr, Nd);
    zero_i32<<<(Nd + 255) / 256, 256, 0, stream>>>(fill, Nd);
    csr_fill<<<(ET + 255) / 256, 256, 0, stream>>>(srcI, dstI, E, nself, rowptr, fill, eidx);
  };
  build_csr(dd_src, dd_dst, EDD, ND, ND, rp_dd, ei_dd);
  build_csr(dt_dst, dt_src, EDT, 0,  ND, rp_rv, ei_rv);
  build_csr(dt_src, dt_dst, EDT, 0,  NT, rp_dt, ei_dt);
  build_csr(tt_src, tt_dst, ETT, NT, NT, rp_tt, ei_tt);

  size_t baseT = (size_t)ND * HDIM;
  size_t baseL = baseT + (size_t)NT * HDIM;

  int nbD = (ND + 3) / 4;   // node-blocks per slice (drug)
  int nbT = (NT + 3) / 4;   // node-blocks per slice (target)

  // 6) per-layer pipeline
  auto run_layer = [&](const int* mD, const int* mT, int mode) {
    row_dot4<<<(ND + 3) / 4, 256, 0, stream>>>(drug_x, mD, mask_drug, vaD, dvec, ND, FD, flag);
    row_dot4<<<(NT + 3) / 4, 256, 0, stream>>>(target_x, mT, mask_target, vaT, tvec, NT, FT, flag);
    {
      long long ta = (long long)ND * KPD / 4;
      pack_a<<<(int)((ta + 255) / 256), 256, 0, stream>>>(drug_x, mD, mask_drug, Ad, ND, FD, KPD, flag);
      ta = (long long)NT * KPT / 4;
      pack_a<<<(int)((ta + 255) / 256), 256, 0, stream>>>(target_x, mT, mask_target, At, NT, FT, KPT, flag);
    }
    dim3 gD(2 * HDIM / BN, (ND + BM - 1) / BM);
    dim3 gT(2 * HDIM / BN, (NT + BM - 1) / BM);
    gemm_mfma<<<gD, 256, 0, stream>>>(Ad, Bd, hs_dd, hs_dt, ND, KPD);
    gemm_mfma<<<gT, 256, 0, stream>>>(At, Bt, hs_rv, hs_tt, NT, KPT);
    // drugs: rel1 = dd (es=dvec.0, ed=dvec.1), rel2 = rv (es=tvec.0, ed=dvec.2)
    gat_gather<<<nbD * NSLICE, 256, 0, stream>>>(
        rp_dd, ei_dd, hs_dd, dvec + 0, dvec + 1,
        rp_rv, ei_rv, hs_rv, tvec + 0, dvec + 2,
        b_dd, b_rv, ND, nbD, d_out, 0, drug_mask, parts, mode, flag);
    // targets: rel1 = dt (es=dvec.3, ed=tvec.1), rel2 = tt (es=tvec.2, ed=tvec.3)
    gat_gather<<<nbT * NSLICE, 256, 0, stream>>>(
        rp_dt, ei_dt, hs_dt, dvec + 3, tvec + 1,
        rp_tt, ei_tt, hs_tt, tvec + 2, tvec + 3,
        b_dt, b_tt, NT, nbT, d_out, baseT, target_mask, parts + 2048, mode, flag);
  };

  run_layer(nullptr, nullptr, 1);          // layer 1
  run_layer(drug_mask, target_mask, 2);    // layer 2 + fused loss
  loss_final<<<1, 256, 0, stream>>>(parts, cnts, d_out, baseL, flag);
}

// Round 3
// 1252.922 us; speedup vs baseline: 1.2690x; 1.2426x over previous
//
#include <hip/hip_runtime.h>
#include <hip/hip_bf16.h>

#define ND 30000
#define NT 15000
#define FD 200
#define FT 570
#define HDIM 768
#define EDD 300000
#define EDT 400000
#define ETT 200000

#define KPD 256   // FD padded to x64 (gather rel1 row: 512B)
#define KPT 576   // FT padded to x64 (gather rel2 row: 1152B)
#define KPA 832   // agg K = KPD + KPT (concat), GEMM K dim

typedef __attribute__((ext_vector_type(8))) short short8;
typedef __attribute__((ext_vector_type(4))) float float4v;

// ---------------- dtype-adaptive load/store ----------------
// flag[0]: 0 = harness float tensors are bf16, 1 = fp32.

__device__ __forceinline__ float ldx(const void* p, size_t i, int f32) {
  return f32 ? ((const float*)p)[i]
             : __bfloat162float(((const __hip_bfloat16*)p)[i]);
}
__device__ __forceinline__ void stx(void* p, size_t i, int f32, float v) {
  if (f32) ((float*)p)[i] = v;
  else     ((__hip_bfloat16*)p)[i] = __float2bfloat16(v);
}
__device__ __forceinline__ float b2f(unsigned short u) {
  return __uint_as_float(((unsigned)u) << 16);
}
__device__ __forceinline__ unsigned short f2b(float f) {
  __hip_bfloat16 h = __float2bfloat16(f);
  return *(unsigned short*)&h;
}
__device__ __forceinline__ unsigned pk2(float a, float b) {
  return (unsigned)f2b(a) | ((unsigned)f2b(b) << 16);
}

__device__ __forceinline__ float wave_reduce(float v) {
#pragma unroll
  for (int off = 32; off > 0; off >>= 1) v += __shfl_xor(v, off, 64);
  return v;
}

// ---------------- dtype sniffer ----------------
__global__ void sniff(const void* x, int* flag) {
  int t = threadIdx.x;
  float cnt = 0.f;
  for (int i = t; i < 8192; i += 256) {
    float v = __bfloat162float(((const __hip_bfloat16*)x)[i]);
    if (!(fabsf(v) < 100.f)) cnt += 1.f;  // true for NaN too
  }
  cnt = wave_reduce(cnt);
  __shared__ float red[4];
  if ((t & 63) == 0) red[t >> 6] = cnt;
  __syncthreads();
  if (t == 0) flag[0] = (red[0] + red[1] + red[2] + red[3] > 256.f) ? 1 : 0;
}

// ---------------- va[k] = sum_h W[k,h]*a[h], one wave per k ----------------
__global__ __launch_bounds__(256) void wa_dot(const void* __restrict__ W, const void* __restrict__ a,
                                              float* __restrict__ outv, int fin,
                                              const int* __restrict__ flag) {
  int f32 = flag[0];
  int k = (blockIdx.x * 256 + threadIdx.x) >> 6;
  int lane = threadIdx.x & 63;
  if (k >= fin) return;
  float acc = 0.f;
  for (int h = lane; h < HDIM; h += 64)
    acc += ldx(W, (size_t)k * HDIM + h, f32) * ldx(a, h, f32);
  acc = wave_reduce(acc);
  if (lane == 0) outv[k] = acc;
}

// ---------- 4 dots per row (shared x read), one wave per row ----------
__global__ __launch_bounds__(256) void row_dot4(const void* __restrict__ x,
                                                const int* __restrict__ mask,
                                                const void* __restrict__ tok,
                                                const float* __restrict__ va,
                                                float* __restrict__ outv, int N, int K,
                                                const int* __restrict__ flag) {
  int f32 = flag[0];
  int row = (blockIdx.x * 256 + threadIdx.x) >> 6;
  int lane = threadIdx.x & 63;
  if (row >= N) return;
  bool msk = (mask != nullptr) && (mask[row] != 0);
  float a0 = 0.f, a1 = 0.f, a2 = 0.f, a3 = 0.f;
  for (int k = lane; k < K; k += 64) {
    float v = msk ? ldx(tok, k, f32) : ldx(x, (size_t)row * K + k, f32);
    a0 += v * va[k];
    a1 += v * va[K + k];
    a2 += v * va[2 * K + k];
    a3 += v * va[3 * K + k];
  }
  a0 = wave_reduce(a0); a1 = wave_reduce(a1);
  a2 = wave_reduce(a2); a3 = wave_reduce(a3);
  if (lane == 0) {
    float* o = outv + (size_t)row * 4;
    o[0] = a0; o[1] = a1; o[2] = a2; o[3] = a3;
  }
}

// ---------------- pack A: x -> bf16 [M][Kp], zero-padded K ----------------
__global__ __launch_bounds__(256) void pack_a(const void* __restrict__ x,
                                              const int* __restrict__ mask,
                                              const void* __restrict__ tok,
                                              unsigned short* __restrict__ Aout,
                                              int M, int K, int Kp,
                                              const int* __restrict__ flag) {
  int f32 = flag[0];
  long long gid = (long long)blockIdx.x * 256 + threadIdx.x;
  long long total = (long long)M * Kp / 4;
  if (gid >= total) return;
  long long e0 = gid * 4;
  int row = (int)(e0 / Kp);
  int k = (int)(e0 % Kp);
  bool msk = (mask != nullptr) && (mask[row] != 0);
  ushort4 o;
  unsigned short r[4];
#pragma unroll
  for (int c = 0; c < 4; ++c) {
    int kk = k + c;
    float f = 0.f;
    if (kk < K) f = msk ? ldx(tok, kk, f32) : ldx(x, (size_t)row * K + kk, f32);
    r[c] = f2b(f);
  }
  o.x = r[0]; o.y = r[1]; o.z = r[2]; o.w = r[3];
  *(ushort4*)(Aout + e0) = o;
}

// ------ pack B^T [768 n][832 k]: k<256 <- W1 (FD rows), k>=256 <- W2 (FT rows) ------
__global__ __launch_bounds__(256) void pack_bTa(const void* __restrict__ W1,
                                                const void* __restrict__ W2,
                                                unsigned short* __restrict__ Bout,
                                                const int* __restrict__ flag) {
  int f32 = flag[0];
  long long gid = (long long)blockIdx.x * 256 + threadIdx.x;
  long long total = (long long)HDIM * KPA / 4;
  if (gid >= total) return;
  long long e0 = gid * 4;
  int n = (int)(e0 / KPA);
  int k = (int)(e0 % KPA);
  ushort4 o;
  unsigned short r[4];
#pragma unroll
  for (int c = 0; c < 4; ++c) {
    int kk = k + c;
    float f = 0.f;
    if (kk < 256) {
      if (kk < FD) f = ldx(W1, (size_t)kk * HDIM + n, f32);
    } else {
      int k2 = kk - 256;
      if (k2 < FT) f = ldx(W2, (size_t)k2 * HDIM + n, f32);
    }
    r[c] = f2b(f);
  }
  o.x = r[0]; o.y = r[1]; o.z = r[2]; o.w = r[3];
  *(ushort4*)(Bout + e0) = o;
}

// ---------------- CSR build ----------------
__global__ void zero_i32(int* __restrict__ p, int n) {
  int i = blockIdx.x * 256 + threadIdx.x;
  if (i < n) p[i] = 0;
}
__global__ void zero_f32(float* __restrict__ p, int n) {
  int i = blockIdx.x * 256 + threadIdx.x;
  if (i < n) p[i] = 0.f;
}

__global__ void csr_count(const int* __restrict__ dst, int E, int nself, int* __restrict__ cnt) {
  int i = blockIdx.x * 256 + threadIdx.x;
  if (i >= E + nself) return;
  int d = (i < E) ? dst[i] : (i - E);
  atomicAdd(&cnt[d], 1);
}

__global__ __launch_bounds__(256) void scan_excl(const int* __restrict__ cnt,
                                                 int* __restrict__ rowptr, int n) {
  __shared__ int part[256];
  int t = threadIdx.x;
  int strip = (n + 255) / 256;
  int lo = min(t * strip, n), hi = min(lo + strip, n);
  int s = 0;
  for (int i = lo; i < hi; ++i) s += cnt[i];
  part[t] = s;
  __syncthreads();
  if (t == 0) {
    int run = 0;
    for (int i = 0; i < 256; ++i) { int v = part[i]; part[i] = run; run += v; }
  }
  __syncthreads();
  int run = part[t];
  for (int i = lo; i < hi; ++i) { rowptr[i] = run; run += cnt[i]; }
  if (hi == n) rowptr[n] = run;
}

__global__ void csr_fill(const int* __restrict__ src, const int* __restrict__ dst, int E, int nself,
                         const int* __restrict__ rowptr, int* __restrict__ fill,
                         int* __restrict__ eidx) {
  int i = blockIdx.x * 256 + threadIdx.x;
  if (i >= E + nself) return;
  int s, d;
  if (i < E) { s = src[i]; d = dst[i]; } else { s = d = i - E; }
  int pos = rowptr[d] + atomicAdd(&fill[d], 1);
  eidx[pos] = s;
}

// ---------------- fused dual-layer GAT aggregation in x-domain ----------------
// agg[dst] = sum_e alpha_e * x_packed[src_e]  (convex combination), for BOTH layers
// in one pass. Layer-2 masked sources collapse to a scalar token weight.
// agg row layout [832]: [0,256)=rel1 cols (uint2/lane), [256,512)=rel2 segA,
// [512,768)=rel2 segB, [768,832)=rel2 segC (1 short/lane).

__device__ __forceinline__ void fma4(float* acc, uint2 A, float al) {
  unsigned w;
  w = A.x; acc[0] += al * __uint_as_float(w << 16); acc[1] += al * __uint_as_float(w & 0xffff0000u);
  w = A.y; acc[2] += al * __uint_as_float(w << 16); acc[3] += al * __uint_as_float(w & 0xffff0000u);
}

__device__ __forceinline__ float alpha_of(float es4, float edv, float inv) {
  float v = es4 + edv;
  v = (v >= 0.f) ? v : 0.2f * v;
  return __expf(v) * inv;
}

__global__ __launch_bounds__(256) void gat_agg2(
    const int* __restrict__ rp1, const int* __restrict__ ei1,
    const unsigned short* __restrict__ A1, const int* __restrict__ msk1,
    const void* __restrict__ tok1,
    const float* __restrict__ es1L1, const float* __restrict__ ed1L1,
    const float* __restrict__ es1L2, const float* __restrict__ ed1L2,
    const int* __restrict__ rp2, const int* __restrict__ ei2,
    const unsigned short* __restrict__ A2, const int* __restrict__ msk2,
    const void* __restrict__ tok2,
    const float* __restrict__ es2L1, const float* __restrict__ ed2L1,
    const float* __restrict__ es2L2, const float* __restrict__ ed2L2,
    int N, unsigned short* __restrict__ agg1, unsigned short* __restrict__ agg2,
    const int* __restrict__ flag) {
  int wid = (blockIdx.x * 256 + threadIdx.x) >> 6;
  int lane = threadIdx.x & 63;
  if (wid >= N) return;
  int f32 = flag[0];
  float ac1[13], ac2[13];
#pragma unroll
  for (int c = 0; c < 13; ++c) { ac1[c] = 0.f; ac2[c] = 0.f; }

  // ---------------- rel1: src rows from A1 [*, KPD] ----------------
  {
    int lo = rp1[wid], hi = rp1[wid + 1];
    float edA = ed1L1[4 * (size_t)wid];
    float edB = ed1L2[4 * (size_t)wid];
    float s1 = 0.f, s2 = 0.f;
    for (int e = lo + lane; e < hi; e += 64) {
      int sn = ei1[e];
      float v1 = es1L1[4 * (size_t)sn] + edA; v1 = (v1 >= 0.f) ? v1 : 0.2f * v1;
      float v2 = es1L2[4 * (size_t)sn] + edB; v2 = (v2 >= 0.f) ? v2 : 0.2f * v2;
      s1 += __expf(v1); s2 += __expf(v2);
    }
    s1 = wave_reduce(s1); s2 = wave_reduce(s2);
    float i1 = 1.f / (s1 + 1e-16f), i2 = 1.f / (s2 + 1e-16f);
    float wt = 0.f;  // layer-2 token weight (wave-uniform)
    int pn = (lo < hi) ? ei1[lo] : 0;
    for (int e = lo; e < hi; ++e) {
      int sn = __builtin_amdgcn_readfirstlane(pn);
      if (e + 1 < hi) pn = ei1[e + 1];
      uint2 rv = *(const uint2*)(A1 + (size_t)sn * KPD + 4 * lane);
      float a1 = alpha_of(es1L1[4 * (size_t)sn], edA, i1);
      float a2 = alpha_of(es1L2[4 * (size_t)sn], edB, i2);
      fma4(ac1, rv, a1);
      if (msk1[sn] != 0) wt += a2;
      else fma4(ac2, rv, a2);
    }
#pragma unroll
    for (int c = 0; c < 4; ++c) {
      int col = 4 * lane + c;
      float tv = (col < FD) ? ldx(tok1, col, f32) : 0.f;
      ac2[c] += wt * tv;
    }
  }

  // ---------------- rel2: src rows from A2 [*, KPT] ----------------
  {
    int lo = rp2[wid], hi = rp2[wid + 1];
    float edA = ed2L1[4 * (size_t)wid];
    float edB = ed2L2[4 * (size_t)wid];
    float s1 = 0.f, s2 = 0.f;
    for (int e = lo + lane; e < hi; e += 64) {
      int sn = ei2[e];
      float v1 = es2L1[4 * (size_t)sn] + edA; v1 = (v1 >= 0.f) ? v1 : 0.2f * v1;
      float v2 = es2L2[4 * (size_t)sn] + edB; v2 = (v2 >= 0.f) ? v2 : 0.2f * v2;
      s1 += __expf(v1); s2 += __expf(v2);
    }
    s1 = wave_reduce(s1); s2 = wave_reduce(s2);
    float i1 = 1.f / (s1 + 1e-16f), i2 = 1.f / (s2 + 1e-16f);
    float wt = 0.f;
    int pn = (lo < hi) ? ei2[lo] : 0;
    for (int e = lo; e < hi; ++e) {
      int sn = __builtin_amdgcn_readfirstlane(pn);
      if (e + 1 < hi) pn = ei2[e + 1];
      const unsigned short* row = A2 + (size_t)sn * KPT;
      uint2 ra = *(const uint2*)(row + 4 * lane);
      uint2 rb = *(const uint2*)(row + 256 + 4 * lane);
      unsigned short rc = row[512 + lane];
      float a1 = alpha_of(es2L1[4 * (size_t)sn], edA, i1);
      float a2 = alpha_of(es2L2[4 * (size_t)sn], edB, i2);
      fma4(ac1 + 4, ra, a1);
      fma4(ac1 + 8, rb, a1);
      ac1[12] += a1 * b2f(rc);
      if (msk2[sn] != 0) {
        wt += a2;
      } else {
        fma4(ac2 + 4, ra, a2);
        fma4(ac2 + 8, rb, a2);
        ac2[12] += a2 * b2f(rc);
      }
    }
#pragma unroll
    for (int c = 0; c < 4; ++c) {
      int colA = 4 * lane + c;          // < 256 < FT
      int colB = 256 + 4 * lane + c;    // < 512 < FT
      ac2[4 + c] += wt * ldx(tok2, colA, f32);
      ac2[8 + c] += wt * ldx(tok2, colB, f32);
    }
    int colC = 512 + lane;
    ac2[12] += wt * ((colC < FT) ? ldx(tok2, colC, f32) : 0.f);
  }

  // ---------------- store both agg rows (bf16) ----------------
  unsigned short* o1 = agg1 + (size_t)wid * KPA;
  unsigned short* o2 = agg2 + (size_t)wid * KPA;
  uint2 u;
  u.x = pk2(ac1[0], ac1[1]);  u.y = pk2(ac1[2], ac1[3]);  *(uint2*)(o1 + 4 * lane) = u;
  u.x = pk2(ac1[4], ac1[5]);  u.y = pk2(ac1[6], ac1[7]);  *(uint2*)(o1 + 256 + 4 * lane) = u;
  u.x = pk2(ac1[8], ac1[9]);  u.y = pk2(ac1[10], ac1[11]); *(uint2*)(o1 + 512 + 4 * lane) = u;
  o1[768 + lane] = f2b(ac1[12]);
  u.x = pk2(ac2[0], ac2[1]);  u.y = pk2(ac2[2], ac2[3]);  *(uint2*)(o2 + 4 * lane) = u;
  u.x = pk2(ac2[4], ac2[5]);  u.y = pk2(ac2[6], ac2[7]);  *(uint2*)(o2 + 256 + 4 * lane) = u;
  u.x = pk2(ac2[8], ac2[9]);  u.y = pk2(ac2[10], ac2[11]); *(uint2*)(o2 + 512 + 4 * lane) = u;
  o2[768 + lane] = f2b(ac2[12]);
}

// ---------------- MFMA GEMM: out[M,768] = agg[M,832] @ B^T[768,832] + b1 + b2 ----
// Epilogue: relu; mode 1 -> store to out; mode 2 -> masked squared diff vs stored.
#define BM 128
#define BN 128
#define BK 64
#define LDK 72   // LDS k-stride (elements): +8 pad

__global__ __launch_bounds__(256) void gemm_out(const unsigned short* __restrict__ A,
                                                const unsigned short* __restrict__ Bt,
                                                const void* __restrict__ b1,
                                                const void* __restrict__ b2,
                                                int M, void* __restrict__ out, size_t base,
                                                const int* __restrict__ mask,
                                                float* __restrict__ parts, int mode,
                                                const int* __restrict__ flag) {
  __shared__ unsigned short Als[BM * LDK];
  __shared__ unsigned short Bls[BN * LDK];
  int t = threadIdx.x;
  int wave = t >> 6, lane = t & 63;
  int quad = lane >> 4, l15 = lane & 15;
  int wrow = (wave & 1) * 64, wcol = (wave >> 1) * 64;
  int m0 = blockIdx.y * BM;
  int n0 = blockIdx.x * BN;
  float4v acc[4][4];
#pragma unroll
  for (int i = 0; i < 4; ++i)
#pragma unroll
    for (int j = 0; j < 4; ++j) acc[i][j] = (float4v){0.f, 0.f, 0.f, 0.f};

  for (int k0 = 0; k0 < KPA; k0 += BK) {
#pragma unroll
    for (int i = 0; i < 4; ++i) {
      int idx = t + i * 256;
      int row = idx >> 3, c = idx & 7;
      uint4 v = make_uint4(0u, 0u, 0u, 0u);
      int gm = m0 + row;
      if (gm < M) v = *(const uint4*)(A + (size_t)gm * KPA + k0 + c * 8);
      *(uint4*)(Als + row * LDK + c * 8) = v;
    }
#pragma unroll
    for (int i = 0; i < 4; ++i) {
      int idx = t + i * 256;
      int row = idx >> 3, c = idx & 7;
      uint4 v = *(const uint4*)(Bt + (size_t)(n0 + row) * KPA + k0 + c * 8);
      *(uint4*)(Bls + row * LDK + c * 8) = v;
    }
    __syncthreads();
#pragma unroll
    for (int kk = 0; kk < 2; ++kk) {
      int koff = kk * 32 + quad * 8;
      short8 a[4], b[4];
#pragma unroll
      for (int i = 0; i < 4; ++i)
        a[i] = *(const short8*)(Als + (wrow + i * 16 + l15) * LDK + koff);
#pragma unroll
      for (int j = 0; j < 4; ++j)
        b[j] = *(const short8*)(Bls + (wcol + j * 16 + l15) * LDK + koff);
#pragma unroll
      for (int i = 0; i < 4; ++i)
#pragma unroll
        for (int j = 0; j < 4; ++j)
          acc[i][j] = __builtin_amdgcn_mfma_f32_16x16x32_bf16(a[i], b[j], acc[i][j], 0, 0, 0);
    }
    __syncthreads();
  }

  // epilogue: C/D layout col=lane&15, row=quad*4+reg
  int f32 = flag[0];
  float bias[4];
#pragma unroll
  for (int j = 0; j < 4; ++j) {
    int n = n0 + wcol + j * 16 + l15;
    bias[j] = ldx(b1, n, f32) + ldx(b2, n, f32);
  }
  float cpart = 0.f;
#pragma unroll
  for (int i = 0; i < 4; ++i) {
    int mbase = m0 + wrow + i * 16 + quad * 4;
#pragma unroll
    for (int j = 0; j < 4; ++j) {
      int n = n0 + wcol + j * 16 + l15;
#pragma unroll
      for (int r = 0; r < 4; ++r) {
        int m = mbase + r;
        if (m < M) {
          float v = acc[i][j][r] + bias[j];
          v = v > 0.f ? v : 0.f;
          size_t idx = base + (size_t)m * HDIM + n;
          if (mode == 1) {
            stx(out, idx, f32, v);
          } else if (mask[m] != 0) {
            float d = ldx(out, idx, f32) - v;
            cpart += d * d;
          }
        }
      }
    }
  }
  if (mode == 2) {
    cpart = wave_reduce(cpart);
    if (lane == 0)
      atomicAdd(&parts[(blockIdx.y * 24 + blockIdx.x * 4 + wave) & 2047], cpart);
  }
}

// ---------------- loss helpers ----------------
__global__ void mask_count(const int* __restrict__ mask, int n, float* __restrict__ cnt) {
  int i = blockIdx.x * 256 + threadIdx.x;
  float v = (i < n && mask[i] != 0) ? 1.f : 0.f;
  v = wave_reduce(v);
  __shared__ float red[4];
  if ((threadIdx.x & 63) == 0) red[threadIdx.x >> 6] = v;
  __syncthreads();
  if (threadIdx.x == 0) atomicAdd(cnt, red[0] + red[1] + red[2] + red[3]);
}

__global__ __launch_bounds__(256) void loss_final(const float* __restrict__ parts,
                                                  const float* __restrict__ cnts,
                                                  void* __restrict__ out, size_t off,
                                                  const int* __restrict__ flag) {
  float a = 0.f, b = 0.f;
  for (int i = threadIdx.x; i < 2048; i += 256) { a += parts[i]; b += parts[2048 + i]; }
  a = wave_reduce(a);
  b = wave_reduce(b);
  __shared__ float ra[4], rb[4];
  if ((threadIdx.x & 63) == 0) { ra[threadIdx.x >> 6] = a; rb[threadIdx.x >> 6] = b; }
  __syncthreads();
  if (threadIdx.x == 0) {
    float sd = ra[0] + ra[1] + ra[2] + ra[3];
    float st = rb[0] + rb[1] + rb[2] + rb[3];
    float loss = sd / (cnts[0] * (float)HDIM + 1e-16f) + st / (cnts[1] * (float)HDIM + 1e-16f);
    stx(out, off, flag[0], loss);
  }
}

// ---------------- host ----------------

extern "C" void kernel_launch(void* const* d_in, const int* in_sizes, int n_in,
                              void* d_out, int out_size, void* d_ws, size_t ws_size,
                              hipStream_t stream) {
  const void* drug_x    = d_in[0];
  const void* target_x  = d_in[1];
  const int* dd_src = (const int*)d_in[2];
  const int* dd_dst = (const int*)d_in[3];
  const int* dt_src = (const int*)d_in[4];
  const int* dt_dst = (const int*)d_in[5];
  const int* tt_src = (const int*)d_in[6];
  const int* tt_dst = (const int*)d_in[7];
  const int* drug_mask   = (const int*)d_in[8];
  const int* target_mask = (const int*)d_in[9];
  const void* mask_drug   = d_in[10];
  const void* mask_target = d_in[11];
  const void* Wsrc_dd = d_in[12]; const void* Wdst_dd = d_in[13];
  const void* asrc_dd = d_in[14]; const void* adst_dd = d_in[15];
  const void* b_dd    = d_in[16];
  const void* Wsrc_dt = d_in[17]; const void* Wdst_dt = d_in[18];
  const void* asrc_dt = d_in[19]; const void* adst_dt = d_in[20];
  const void* b_dt    = d_in[21];
  const void* Wsrc_rv = d_in[22]; const void* Wdst_rv = d_in[23];
  const void* asrc_rv = d_in[24]; const void* adst_rv = d_in[25];
  const void* b_rv    = d_in[26];
  const void* Wsrc_tt = d_in[27]; const void* Wdst_tt = d_in[28];
  const void* asrc_tt = d_in[29]; const void* adst_tt = d_in[30];
  const void* b_tt    = d_in[31];

  char* p = (char*)d_ws;
  auto alloc = [&](size_t bytes) -> void* {
    void* r = (void*)p;
    p += (bytes + 255) & ~(size_t)255;
    return r;
  };
  unsigned short* Ad    = (unsigned short*)alloc((size_t)ND * KPD * 2);
  unsigned short* At    = (unsigned short*)alloc((size_t)NT * KPT * 2);
  unsigned short* aggd1 = (unsigned short*)alloc((size_t)ND * KPA * 2);
  unsigned short* aggd2 = (unsigned short*)alloc((size_t)ND * KPA * 2);
  unsigned short* aggt1 = (unsigned short*)alloc((size_t)NT * KPA * 2);
  unsigned short* aggt2 = (unsigned short*)alloc((size_t)NT * KPA * 2);
  unsigned short* BdW   = (unsigned short*)alloc((size_t)HDIM * KPA * 2);
  unsigned short* BtW   = (unsigned short*)alloc((size_t)HDIM * KPA * 2);
  float* dvec1 = (float*)alloc((size_t)ND * 4 * 4);   // L1 {es_dd, ed_dd, ed_rv, es_dt}
  float* dvec2 = (float*)alloc((size_t)ND * 4 * 4);   // L2 same components
  float* tvec1 = (float*)alloc((size_t)NT * 4 * 4);   // L1 {es_rv, ed_dt, es_tt, ed_tt}
  float* tvec2 = (float*)alloc((size_t)NT * 4 * 4);   // L2
  int* rp_dd = (int*)alloc((size_t)(ND + 1) * 4);
  int* rp_rv = (int*)alloc((size_t)(ND + 1) * 4);
  int* rp_dt = (int*)alloc((size_t)(NT + 1) * 4);
  int* rp_tt = (int*)alloc((size_t)(NT + 1) * 4);
  int* ei_dd = (int*)alloc((size_t)(EDD + ND) * 4);
  int* ei_rv = (int*)alloc((size_t)EDT * 4);
  int* ei_dt = (int*)alloc((size_t)EDT * 4);
  int* ei_tt = (int*)alloc((size_t)(ETT + NT) * 4);
  int* cnt   = (int*)alloc((size_t)ND * 4);
  int* fill  = (int*)alloc((size_t)ND * 4);
  float* vaD = (float*)alloc((size_t)4 * FD * 4);
  float* vaT = (float*)alloc((size_t)4 * FT * 4);
  float* parts = (float*)alloc((size_t)(4096 + 2) * 4);
  float* cnts  = parts + 4096;
  int*   flag  = (int*)alloc(256);

  // 1) dtype sniff
  sniff<<<1, 256, 0, stream>>>(drug_x, flag);

  // 2) zero loss partials + mask counters
  zero_f32<<<(4098 + 255) / 256, 256, 0, stream>>>(parts, 4098);
  mask_count<<<(ND + 255) / 256, 256, 0, stream>>>(drug_mask, ND, cnts + 0);
  mask_count<<<(NT + 255) / 256, 256, 0, stream>>>(target_mask, NT, cnts + 1);

  // 3) va vectors (attention projections in x-domain)
  struct { const void* W; const void* a; int fin; float* out; } vas[8] = {
    {Wsrc_dd, asrc_dd, FD, vaD + 0 * FD}, {Wdst_dd, adst_dd, FD, vaD + 1 * FD},
    {Wdst_rv, adst_rv, FD, vaD + 2 * FD}, {Wsrc_dt, asrc_dt, FD, vaD + 3 * FD},
    {Wsrc_rv, asrc_rv, FT, vaT + 0 * FT}, {Wdst_dt, adst_dt, FT, vaT + 1 * FT},
    {Wsrc_tt, asrc_tt, FT, vaT + 2 * FT}, {Wdst_tt, adst_tt, FT, vaT + 3 * FT},
  };
  for (int i = 0; i < 8; ++i)
    wa_dot<<<(vas[i].fin * 64 + 255) / 256, 256, 0, stream>>>(vas[i].W, vas[i].a,
                                                              vas[i].out, vas[i].fin, flag);

  // 4) pack concat weights: drug out B = [Wsrc_dd ; Wsrc_rv], target B = [Wsrc_dt ; Wsrc_tt]
  {
    int g = (int)(((long long)HDIM * KPA / 4 + 255) / 256);
    pack_bTa<<<g, 256, 0, stream>>>(Wsrc_dd, Wsrc_rv, BdW, flag);
    pack_bTa<<<g, 256, 0, stream>>>(Wsrc_dt, Wsrc_tt, BtW, flag);
  }

  // 5) CSR build
  auto build_csr = [&](const int* srcI, const int* dstI, int E, int nself, int Nd,
                       int* rowptr, int* eidx) {
    int ET = E + nself;
    zero_i32<<<(Nd + 255) / 256, 256, 0, stream>>>(cnt, Nd);
    csr_count<<<(ET + 255) / 256, 256, 0, stream>>>(dstI, E, nself, cnt);
    scan_excl<<<1, 256, 0, stream>>>(cnt, rowptr, Nd);
    zero_i32<<<(Nd + 255) / 256, 256, 0, stream>>>(fill, Nd);
    csr_fill<<<(ET + 255) / 256, 256, 0, stream>>>(srcI, dstI, E, nself, rowptr, fill, eidx);
  };
  build_csr(dd_src, dd_dst, EDD, ND, ND, rp_dd, ei_dd);
  build_csr(dt_dst, dt_src, EDT, 0,  ND, rp_rv, ei_rv);
  build_csr(dt_src, dt_dst, EDT, 0,  NT, rp_dt, ei_dt);
  build_csr(tt_src, tt_dst, ETT, NT, NT, rp_tt, ei_tt);

  // 6) pack unmasked x (single source for both layers' gathers)
  {
    long long ta = (long long)ND * KPD / 4;
    pack_a<<<(int)((ta + 255) / 256), 256, 0, stream>>>(drug_x, nullptr, mask_drug, Ad, ND, FD, KPD, flag);
    ta = (long long)NT * KPT / 4;
    pack_a<<<(int)((ta + 255) / 256), 256, 0, stream>>>(target_x, nullptr, mask_target, At, NT, FT, KPT, flag);
  }

  // 7) es/ed tables for both layers
  row_dot4<<<(ND + 3) / 4, 256, 0, stream>>>(drug_x, nullptr, mask_drug, vaD, dvec1, ND, FD, flag);
  row_dot4<<<(NT + 3) / 4, 256, 0, stream>>>(target_x, nullptr, mask_target, vaT, tvec1, NT, FT, flag);
  row_dot4<<<(ND + 3) / 4, 256, 0, stream>>>(drug_x, drug_mask, mask_drug, vaD, dvec2, ND, FD, flag);
  row_dot4<<<(NT + 3) / 4, 256, 0, stream>>>(target_x, target_mask, mask_target, vaT, tvec2, NT, FT, flag);

  // 8) combined dual-layer gathers (x-domain)
  // drug dst: rel1 = dd (src drug), rel2 = rv (src target)
  gat_agg2<<<(ND + 3) / 4, 256, 0, stream>>>(
      rp_dd, ei_dd, Ad, drug_mask, mask_drug,
      dvec1 + 0, dvec1 + 1, dvec2 + 0, dvec2 + 1,
      rp_rv, ei_rv, At, target_mask, mask_target,
      tvec1 + 0, dvec1 + 2, tvec2 + 0, dvec2 + 2,
      ND, aggd1, aggd2, flag);
  // target dst: rel1 = dt (src drug), rel2 = tt (src target)
  gat_agg2<<<(NT + 3) / 4, 256, 0, stream>>>(
      rp_dt, ei_dt, Ad, drug_mask, mask_drug,
      dvec1 + 3, tvec1 + 1, dvec2 + 3, tvec2 + 1,
      rp_tt, ei_tt, At, target_mask, mask_target,
      tvec1 + 2, tvec1 + 3, tvec2 + 2, tvec2 + 3,
      NT, aggt1, aggt2, flag);

  size_t baseT = (size_t)ND * HDIM;
  size_t baseL = baseT + (size_t)NT * HDIM;

  // 9) output GEMMs (layer1 stores, layer2 computes fused loss)
  dim3 gD(HDIM / BN, (ND + BM - 1) / BM);
  dim3 gT(HDIM / BN, (NT + BM - 1) / BM);
  gemm_out<<<gD, 256, 0, stream>>>(aggd1, BdW, b_dd, b_rv, ND, d_out, 0,
                                   nullptr, parts, 1, flag);
  gemm_out<<<gT, 256, 0, stream>>>(aggt1, BtW, b_dt, b_tt, NT, d_out, baseT,
                                   nullptr, parts, 1, flag);
  gemm_out<<<gD, 256, 0, stream>>>(aggd2, BdW, b_dd, b_rv, ND, d_out, 0,
                                   drug_mask, parts, 2, flag);
  gemm_out<<<gT, 256, 0, stream>>>(aggt2, BtW, b_dt, b_tt, NT, d_out, baseT,
                                   target_mask, parts + 2048, 2, flag);

  loss_final<<<1, 256, 0, stream>>>(parts, cnts, d_out, baseL, flag);
}